// Round 6
// baseline (669.614 us; speedup 1.0000x reference)
//
#include <hip/hip_runtime.h>

typedef __bf16 bf16;
typedef __bf16 bf16x8 __attribute__((ext_vector_type(8)));
typedef __bf16 bf16x4 __attribute__((ext_vector_type(4)));
typedef float  floatx4 __attribute__((ext_vector_type(4)));

#define HIDDEN   2048
#define NUMH     64
#define HDIM     64
#define STATE    128
#define INTER    4096
#define CONV_DIM 4352
#define PROJ_N   8512
#define PROJ_PAD 8576
#define SEQ      2048
#define BATCH    2
#define CHUNK    256
#define NCHUNK   8
#define ROWS     4096   // BATCH*SEQ
#define DT_COL0  8448   // INTER + CONV_DIM

// async global->LDS, 16B per lane, LDS dest = wave-uniform base + lane*16
#define GLDS(gp, lp) __builtin_amdgcn_global_load_lds(                      \
    (const __attribute__((address_space(1))) void*)(gp),                    \
    (__attribute__((address_space(3))) void*)(lp), 16, 0, 0)

// ------------------------------------------------- f32 -> bf16 (8/thread)
__global__ __launch_bounds__(256) void cvt_bf16_kernel(
    const float* __restrict__ in, bf16* __restrict__ out, long n, long srcn) {
  long i = ((long)blockIdx.x * 256 + threadIdx.x) * 8;
  if (i >= n) return;
  if (i + 7 < srcn) {
    const float4* p = (const float4*)(in + i);
    float4 a = p[0], b = p[1];
    bf16x8 o;
    o[0] = (bf16)a.x; o[1] = (bf16)a.y; o[2] = (bf16)a.z; o[3] = (bf16)a.w;
    o[4] = (bf16)b.x; o[5] = (bf16)b.y; o[6] = (bf16)b.z; o[7] = (bf16)b.w;
    *(bf16x8*)(out + i) = o;
  } else {
    for (int j = 0; j < 8; j++) {
      float v = (i + j < srcn) ? in[i + j] : 0.f;
      out[i + j] = (bf16)v;
    }
  }
}

// ------------------------------------------------------- bf16 MFMA GEMM (BT)
// round-0 proven m97-structure kernel. Templated on min-waves/EU:
//   WPE=4 -> 128-reg cap, 4 blocks/CU (gemm1 occupancy experiment;
//            current use = 56 VGPR + 64 AGPR = 120 unified, fits)
//   WPE=2 -> control (round-0/4 codegen) for gemm2
template <int WPE>
__global__ __launch_bounds__(256, WPE) void gemm_bt_kernel(
    const bf16* __restrict__ A, const bf16* __restrict__ B,
    const float* __restrict__ bias, bf16* __restrict__ Cb,
    float* __restrict__ Cf, float* __restrict__ ds,
    int M, int N, int K, int bias_n, int dt0) {
  __shared__ __align__(16) bf16 lA[2 * 128 * 32];
  __shared__ __align__(16) bf16 lB[2 * 128 * 32];
  const int tid  = threadIdx.x;
  const int lane = tid & 63;
  const int wave = tid >> 6;
  const int gm = M >> 7;
  const int id = blockIdx.x;
  const int xcd = id & 7;
  const int j = id >> 3;
  const int mstripe = gm >> 3;
  const int mb = xcd * mstripe + (j % mstripe);
  const int nb = j / mstripe;
  const int m0 = mb * 128;
  const int n0 = nb * 128;
  const int wm = (wave >> 1) * 64;
  const int wn = (wave & 1) * 64;
  const int q  = lane >> 4;     // 0..3
  const int ln = lane & 15;
  const int r0 = tid >> 2;      // 0..63
  const int c0 = (tid & 3) * 8; // 0,8,16,24

  floatx4 acc[4][4] = {};

  const bf16* Ap = A + (long)(m0 + r0) * K + c0;
  const bf16* Bp = B + (long)(n0 + r0) * K + c0;
  bf16* lAw = lA + wave * 512;   // wave-uniform LDS base (lane*16B appended)
  bf16* lBw = lB + wave * 512;

  for (int k0 = 0; k0 < K; k0 += 64) {
    __syncthreads();
    GLDS(Ap + k0, lAw);
    GLDS(Ap + (long)64 * K + k0, lAw + 2048);
    GLDS(Ap + k0 + 32, lAw + 4096);
    GLDS(Ap + (long)64 * K + k0 + 32, lAw + 6144);
    GLDS(Bp + k0, lBw);
    GLDS(Bp + (long)64 * K + k0, lBw + 2048);
    GLDS(Bp + k0 + 32, lBw + 4096);
    GLDS(Bp + (long)64 * K + k0 + 32, lBw + 6144);
    __syncthreads();
#pragma unroll
    for (int kc = 0; kc < 2; kc++) {
      bf16x8 af[4], bg[4];
#pragma unroll
      for (int i = 0; i < 4; i++) {
        af[i] = *(const bf16x8*)(lA + kc * 4096 + (wm + i * 16 + ln) * 32 + q * 8);
        bg[i] = *(const bf16x8*)(lB + kc * 4096 + (wn + i * 16 + ln) * 32 + q * 8);
      }
#pragma unroll
      for (int mi = 0; mi < 4; mi++)
#pragma unroll
        for (int ni = 0; ni < 4; ni++)
          acc[mi][ni] = __builtin_amdgcn_mfma_f32_16x16x32_bf16(
              af[mi], bg[ni], acc[mi][ni], 0, 0, 0);
    }
  }

#pragma unroll
  for (int mi = 0; mi < 4; mi++) {
#pragma unroll
    for (int ni = 0; ni < 4; ni++) {
      int col = n0 + wn + ni * 16 + ln;
      float bv = (col < bias_n) ? bias[col] : 0.f;
#pragma unroll
      for (int r = 0; r < 4; r++) {
        int row = m0 + wm + mi * 16 + q * 4 + r;
        float v = acc[mi][ni][r] + bv;
        if (Cb) Cb[(long)row * N + col] = (bf16)v;
        else    Cf[(long)row * N + col] = v;
        if (ds && col >= dt0 && col < dt0 + 64)
          ds[(long)row * 64 + (col - dt0)] = v;
      }
    }
  }
}

// ------------------------------------------- causal conv4 + SiLU (8/thread)
__global__ __launch_bounds__(256) void conv_silu_kernel(
    const bf16* __restrict__ proj, const float* __restrict__ cw,
    bf16* __restrict__ out) {
  long i = ((long)blockIdx.x * 256 + threadIdx.x) * 8;
  if (i >= (long)ROWS * CONV_DIM) return;
  int ch = (int)(i % CONV_DIM);        // multiple of 8 (CONV_DIM % 8 == 0)
  long bl = i / CONV_DIM;
  int l = (int)(bl & (SEQ - 1));
  const bf16* p = proj + bl * PROJ_PAD + INTER + ch;
  float a[8] = {};
#pragma unroll
  for (int tap = 0; tap < 4; tap++) {
    int back = 3 - tap;
    if (l >= back) {
      bf16x8 v = *(const bf16x8*)(p - (long)back * PROJ_PAD);
#pragma unroll
      for (int j = 0; j < 8; j++) a[j] += (float)v[j] * cw[(ch + j) * 4 + tap];
    }
  }
  bf16x8 o;
#pragma unroll
  for (int j = 0; j < 8; j++) {
    float s = a[j] / (1.f + expf(-a[j]));
    o[j] = (bf16)s;
  }
  *(bf16x8*)(out + i) = o;
}

// ---------------------------------------------- dt softplus + per-chunk scan
__global__ __launch_bounds__(256) void dt_scan_kernel(
    const float* __restrict__ dtraw, const float* __restrict__ dt_bias,
    const float* __restrict__ A_log, float* __restrict__ dtb,
    float* __restrict__ cumA) {
  int idx = blockIdx.x;
  int c = idx & 7, h = (idx >> 3) & 63, b = idx >> 9;
  int s = threadIdx.x;
  long row = (long)b * SEQ + c * CHUNK + s;
  float x = dtraw[row * NUMH + h] + dt_bias[h];
  float dt = (x > 20.f) ? x : log1pf(expf(x));
  dtb[row * NUMH + h] = dt;
  float dA = -expf(A_log[h]) * dt;
  __shared__ float sc[256];
  sc[s] = dA;
  __syncthreads();
  for (int off = 1; off < 256; off <<= 1) {
    float v = (s >= off) ? sc[s - off] : 0.f;
    __syncthreads();
    sc[s] += v;
    __syncthreads();
  }
  cumA[(long)idx * 256 + s] = sc[s];
}

// ------------------------------------------------- G = C @ B^T  (MFMA)
__global__ __launch_bounds__(256, 2) void g_kernel(
    const bf16* __restrict__ conv, float* __restrict__ G) {
  int bc = blockIdx.x, tt = blockIdx.y, sb = blockIdx.z;
  if (sb > tt) return;  // upper triangle never read
  int b = bc >> 3, c = bc & 7;
  int tid = threadIdx.x, lane = tid & 63, w = tid >> 6;
  int q = lane >> 4, ln = lane & 15;
  __shared__ __align__(16) bf16 sCg[4 * 64 * 32];  // [(kc*64+t)*32 + (n&31)]
  __shared__ __align__(16) bf16 sBg[4 * 64 * 32];
  long rowBase = (long)b * SEQ + c * CHUNK;
  for (int i = tid; i < 1024; i += 256) {
    int r = i >> 4, n0 = (i & 15) * 8;
    int base = ((n0 >> 5) * 64 + r) * 32 + (n0 & 31);
    bf16x8 cv = *(const bf16x8*)(conv + (rowBase + tt * 64 + r) * CONV_DIM + INTER + STATE + n0);
    *(bf16x8*)(sCg + base) = cv;
    bf16x8 bv = *(const bf16x8*)(conv + (rowBase + sb * 64 + r) * CONV_DIM + INTER + n0);
    *(bf16x8*)(sBg + base) = bv;
  }
  __syncthreads();
  floatx4 acc[4] = {};
#pragma unroll
  for (int kc = 0; kc < 4; kc++) {
    bf16x8 af = *(const bf16x8*)(sCg + (kc * 64 + w * 16 + ln) * 32 + q * 8);
#pragma unroll
    for (int ni = 0; ni < 4; ni++) {
      bf16x8 bg = *(const bf16x8*)(sBg + (kc * 64 + ni * 16 + ln) * 32 + q * 8);
      acc[ni] = __builtin_amdgcn_mfma_f32_16x16x32_bf16(af, bg, acc[ni], 0, 0, 0);
    }
  }
  float* Gb = G + ((long)bc << 16);
#pragma unroll
  for (int ni = 0; ni < 4; ni++) {
    int s = sb * 64 + ni * 16 + ln;
#pragma unroll
    for (int r = 0; r < 4; r++) {
      int t = tt * 64 + w * 16 + q * 4 + r;
      Gb[(long)t * 256 + s] = acc[ni][r];
    }
  }
}

// --------------------------------------- per-chunk states S = B^T·(x·w) MFMA
__global__ __launch_bounds__(256, 2) void states_kernel(
    const bf16* __restrict__ conv, const float* __restrict__ dtb,
    const float* __restrict__ cumA, float* __restrict__ S) {
  int idx = blockIdx.x;  // ((b*8+c)*64+h)
  int h = idx & 63, c = (idx >> 6) & 7, b = idx >> 9;
  int tid = threadIdx.x, lane = tid & 63, w = tid >> 6;
  int q = lane >> 4, ln = lane & 15;
  __shared__ __align__(16) bf16 sBT[2 * 128 * 32];  // [(kc*128+n)*32 + (s&31)]
  __shared__ __align__(16) bf16 sXT[2 * 64 * 32];   // [(kc*64+p)*32 + (s&31)]
  long caBase = ((long)(b * 64 + h) * 8 + c) * 256;
  float aLast = cumA[caBase + 255];
  long rowBase = (long)b * SEQ + c * CHUNK;
  floatx4 acc[2][4] = {};
  for (int s0 = 0; s0 < 256; s0 += 64) {
    __syncthreads();
    for (int i = tid; i < 1024; i += 256) {
      int sl = i >> 4, n0 = (i & 15) * 8;
      bf16x8 v = *(const bf16x8*)(conv + (rowBase + s0 + sl) * CONV_DIM + INTER + n0);
      int base = ((sl >> 5) * 128 + n0) * 32 + (sl & 31);
#pragma unroll
      for (int jj = 0; jj < 8; jj++) sBT[base + jj * 32] = v[jj];
    }
    for (int i = tid; i < 512; i += 256) {
      int sl = i >> 3, p0 = (i & 7) * 8;
      long row = rowBase + s0 + sl;
      float wgt = __expf(aLast - cumA[caBase + s0 + sl]) * dtb[row * NUMH + h];
      bf16x8 v = *(const bf16x8*)(conv + row * CONV_DIM + h * HDIM + p0);
      int base = ((sl >> 5) * 64 + p0) * 32 + (sl & 31);
#pragma unroll
      for (int jj = 0; jj < 8; jj++) sXT[base + jj * 32] = (bf16)((float)v[jj] * wgt);
    }
    __syncthreads();
#pragma unroll
    for (int kc = 0; kc < 2; kc++) {
      bf16x8 af[2], bg[4];
#pragma unroll
      for (int mi = 0; mi < 2; mi++)
        af[mi] = *(const bf16x8*)(sBT + (kc * 128 + w * 32 + mi * 16 + ln) * 32 + q * 8);
#pragma unroll
      for (int ni = 0; ni < 4; ni++)
        bg[ni] = *(const bf16x8*)(sXT + (kc * 64 + ni * 16 + ln) * 32 + q * 8);
#pragma unroll
      for (int mi = 0; mi < 2; mi++)
#pragma unroll
        for (int ni = 0; ni < 4; ni++)
          acc[mi][ni] = __builtin_amdgcn_mfma_f32_16x16x32_bf16(
              af[mi], bg[ni], acc[mi][ni], 0, 0, 0);
    }
  }
  float* Sp = S + ((long)idx << 13);
#pragma unroll
  for (int mi = 0; mi < 2; mi++)
#pragma unroll
    for (int ni = 0; ni < 4; ni++) {
      int p = ni * 16 + ln;
#pragma unroll
      for (int r = 0; r < 4; r++) {
        int n = w * 32 + mi * 16 + q * 4 + r;
        Sp[n * 64 + p] = acc[mi][ni][r];
      }
    }
}

// ---------------------------------------- inter-chunk recurrence (b,h,kq)
__global__ __launch_bounds__(256) void recur_kernel(
    const float* __restrict__ S, const float* __restrict__ cumA,
    float* __restrict__ P) {
  int bh = blockIdx.x, kq = blockIdx.y;
  int b = bh >> 6, h = bh & 63;
  int tid = threadIdx.x;
  float p[8];
#pragma unroll
  for (int k = 0; k < 8; k++) p[k] = 0.f;
  for (int c = 0; c < 8; c++) {
    long blk = ((long)(b * 8 + c) * 64 + h) << 13;
#pragma unroll
    for (int k = 0; k < 8; k++) P[blk + (kq * 8 + k) * 256 + tid] = p[k];
    float e = __expf(cumA[((long)bh * 8 + c) * 256 + 255]);
#pragma unroll
    for (int k = 0; k < 8; k++) p[k] = S[blk + (kq * 8 + k) * 256 + tid] + e * p[k];
  }
}

// ------------------------------------------------ Y = diag + off + D*x (MFMA)
// off-diag decay factored: exp(cAt-cAs) = exp(cAt-cAend(sb)) * sE[s], both <=1
__global__ __launch_bounds__(256, 2) void y_kernel(
    const bf16* __restrict__ conv, const float* __restrict__ dtb,
    const float* __restrict__ cumA, const float* __restrict__ G,
    const float* __restrict__ P, const float* __restrict__ D,
    bf16* __restrict__ ybuf) {
  int idx = blockIdx.x;  // ((b*8+c)*64+h)
  int h = idx & 63, c = (idx >> 6) & 7, b = idx >> 9;
  int tid = threadIdx.x, lane = tid & 63, w = tid >> 6;
  int q = lane >> 4, ln = lane & 15;
  __shared__ __align__(16) bf16 sPT[128 * 64];   // ((n>>5)*64+p)*32+(n&31)
  __shared__ __align__(16) bf16 sXT[256 * 64];   // ((s>>5)*64+p)*32+(s&31)
  __shared__ float scA[256];
  __shared__ float sE[256];                      // exp(cA[s|63] - cA[s]) <= 1
  long caBase = ((long)(b * 64 + h) * 8 + c) * 256;
  long rowBase = (long)b * SEQ + c * CHUNK;
  const float* Gbase = G + ((long)(b * 8 + c) << 16);

  float myA = cumA[caBase + tid];
  scA[tid] = myA;
  {
    const float* Pblk = P + ((long)idx << 13);
    int n = tid >> 1;
    int p0 = (tid & 1) * 32;
    int nc = (n >> 5) * 64, nk = n & 31;
#pragma unroll
    for (int pp = 0; pp < 32; pp += 4) {
      floatx4 v = *(const floatx4*)(Pblk + n * 64 + p0 + pp);
#pragma unroll
      for (int j = 0; j < 4; j++)
        sPT[(nc + p0 + pp + j) * 32 + nk] = (bf16)v[j];
    }
  }
  {
    int s = tid;
    long row = rowBase + s;
    float dt = dtb[row * NUMH + h];
    int sc = (s >> 5) * 64, sk = s & 31;
    const bf16* xr = conv + row * CONV_DIM + h * HDIM;
#pragma unroll
    for (int p0 = 0; p0 < 64; p0 += 8) {
      bf16x8 xv = *(const bf16x8*)(xr + p0);
#pragma unroll
      for (int j = 0; j < 8; j++)
        sXT[(sc + p0 + j) * 32 + sk] = (bf16)((float)xv[j] * dt);
    }
  }
  __syncthreads();
  sE[tid] = __expf(scA[tid | 63] - myA);

  floatx4 acc[4][4] = {};

  // phase 1: Y_off = C @ P^T
  const bf16* Cbase = conv + (rowBase + w * 64) * CONV_DIM + INTER + STATE;
  for (int k0 = 0; k0 < 128; k0 += 32) {
    bf16x8 af[4], bg[4];
#pragma unroll
    for (int mi = 0; mi < 4; mi++)
      af[mi] = *(const bf16x8*)(Cbase + (long)(mi * 16 + ln) * CONV_DIM + k0 + q * 8);
#pragma unroll
    for (int ni = 0; ni < 4; ni++)
      bg[ni] = *(const bf16x8*)(sPT + ((k0 >> 5) * 64 + ni * 16 + ln) * 32 + q * 8);
#pragma unroll
    for (int mi = 0; mi < 4; mi++)
#pragma unroll
      for (int ni = 0; ni < 4; ni++)
        acc[mi][ni] = __builtin_amdgcn_mfma_f32_16x16x32_bf16(
            af[mi], bg[ni], acc[mi][ni], 0, 0, 0);
  }
#pragma unroll
  for (int mi = 0; mi < 4; mi++)
#pragma unroll
    for (int r = 0; r < 4; r++) {
      float e = __expf(scA[w * 64 + mi * 16 + q * 4 + r]);
#pragma unroll
      for (int ni = 0; ni < 4; ni++) acc[mi][ni][r] *= e;
    }
  __syncthreads();  // sE visible to all waves

  // phase 2a: off-diagonal s-blocks (factored decay, no per-element expf)
  for (int sb = 0; sb < w; sb++) {
    float Rm[4];
#pragma unroll
    for (int mi = 0; mi < 4; mi++)
      Rm[mi] = __expf(scA[w * 64 + mi * 16 + ln] - scA[sb * 64 + 63]);
#pragma unroll
    for (int kk = 0; kk < 64; kk += 32) {
      int s0 = sb * 64 + kk;
      bf16x8 af[4], bg[4];
#pragma unroll
      for (int mi = 0; mi < 4; mi++) {
        int t = w * 64 + mi * 16 + ln;
        const float* Gr = Gbase + (long)t * 256 + s0 + q * 8;
        floatx4 g0 = *(const floatx4*)Gr;
        floatx4 g1 = *(const floatx4*)(Gr + 4);
        bf16x8 m;
#pragma unroll
        for (int j = 0; j < 4; j++)
          m[j] = (bf16)(g0[j] * Rm[mi] * sE[s0 + q * 8 + j]);
#pragma unroll
        for (int j = 4; j < 8; j++)
          m[j] = (bf16)(g1[j - 4] * Rm[mi] * sE[s0 + q * 8 + j]);
        af[mi] = m;
      }
#pragma unroll
      for (int ni = 0; ni < 4; ni++)
        bg[ni] = *(const bf16x8*)(sXT + ((s0 >> 5) * 64 + ni * 16 + ln) * 32 + q * 8);
#pragma unroll
      for (int mi = 0; mi < 4; mi++)
#pragma unroll
        for (int ni = 0; ni < 4; ni++)
          acc[mi][ni] = __builtin_amdgcn_mfma_f32_16x16x32_bf16(
              af[mi], bg[ni], acc[mi][ni], 0, 0, 0);
    }
  }

  // phase 2b: diagonal s-block (per-element expf + causal mask)
  {
    int sb = w;
#pragma unroll
    for (int kk = 0; kk < 64; kk += 32) {
      int s0 = sb * 64 + kk;
      bf16x8 af[4], bg[4];
#pragma unroll
      for (int mi = 0; mi < 4; mi++) {
        int t = w * 64 + mi * 16 + ln;
        float cAt = scA[t];
        const float* Gr = Gbase + (long)t * 256 + s0 + q * 8;
        floatx4 g0 = *(const floatx4*)Gr;
        floatx4 g1 = *(const floatx4*)(Gr + 4);
        bf16x8 m;
#pragma unroll
        for (int j = 0; j < 4; j++) {
          int s = s0 + q * 8 + j;
          float v = g0[j] * __expf(cAt - scA[s]);
          m[j] = (bf16)((s <= t) ? v : 0.f);
        }
#pragma unroll
        for (int j = 4; j < 8; j++) {
          int s = s0 + q * 8 + j;
          float v = g1[j - 4] * __expf(cAt - scA[s]);
          m[j] = (bf16)((s <= t) ? v : 0.f);
        }
        af[mi] = m;
      }
#pragma unroll
      for (int ni = 0; ni < 4; ni++)
        bg[ni] = *(const bf16x8*)(sXT + ((s0 >> 5) * 64 + ni * 16 + ln) * 32 + q * 8);
#pragma unroll
      for (int mi = 0; mi < 4; mi++)
#pragma unroll
        for (int ni = 0; ni < 4; ni++)
          acc[mi][ni] = __builtin_amdgcn_mfma_f32_16x16x32_bf16(
              af[mi], bg[ni], acc[mi][ni], 0, 0, 0);
    }
  }

  float d = D[h];
#pragma unroll
  for (int mi = 0; mi < 4; mi++)
#pragma unroll
    for (int ni = 0; ni < 4; ni++) {
      int col = ni * 16 + ln;
#pragma unroll
      for (int r = 0; r < 4; r++) {
        long row = rowBase + w * 64 + mi * 16 + q * 4 + r;
        float xv = (float)conv[row * CONV_DIM + h * HDIM + col];
        ybuf[row * INTER + h * HDIM + col] = (bf16)(acc[mi][ni][r] + d * xv);
      }
    }
}

// --------------------------------- gated RMSNorm->bf16 (vectorized bf16x8)
__global__ __launch_bounds__(256) void rmsnorm_kernel(
    const bf16* __restrict__ ybuf, const bf16* __restrict__ proj,
    const float* __restrict__ nw, bf16* __restrict__ gb) {
  long row = blockIdx.x;
  int tid = threadIdx.x;
  float gv[16];
  float ss = 0.f;
#pragma unroll
  for (int h = 0; h < 2; h++) {
    int i = h * 2048 + tid * 8;
    bf16x8 yv = *(const bf16x8*)(ybuf + row * INTER + i);
    bf16x8 gt = *(const bf16x8*)(proj + row * PROJ_PAD + i);
#pragma unroll
    for (int j = 0; j < 8; j++) {
      float y = (float)yv[j];
      float g = (float)gt[j];
      float gg = y * (g / (1.f + expf(-g)));
      gv[h * 8 + j] = gg;
      ss += gg * gg;
    }
  }
#pragma unroll
  for (int off = 32; off > 0; off >>= 1) ss += __shfl_down(ss, off, 64);
  __shared__ float red[4];
  if ((tid & 63) == 0) red[tid >> 6] = ss;
  __syncthreads();
  float tot = red[0] + red[1] + red[2] + red[3];
  float scale = rsqrtf(tot * (1.f / 4096.f) + 1e-5f);
#pragma unroll
  for (int h = 0; h < 2; h++) {
    int i = h * 2048 + tid * 8;
    bf16x8 o;
#pragma unroll
    for (int j = 0; j < 8; j++)
      o[j] = (bf16)(gv[h * 8 + j] * scale * nw[i + j]);
    *(bf16x8*)(gb + row * INTER + i) = o;
  }
}

// ============================================================== launch
extern "C" void kernel_launch(void* const* d_in, const int* in_sizes, int n_in,
                              void* d_out, int out_size, void* d_ws, size_t ws_size,
                              hipStream_t stream) {
  const float* hs   = (const float*)d_in[0];
  const float* ipw  = (const float*)d_in[1];
  const float* ipb  = (const float*)d_in[2];
  const float* cw   = (const float*)d_in[3];
  const float* dtbi = (const float*)d_in[4];
  const float* alog = (const float*)d_in[5];
  const float* Dp   = (const float*)d_in[6];
  const float* nw   = (const float*)d_in[7];
  const float* opw  = (const float*)d_in[8];
  const float* opb  = (const float*)d_in[9];
  float* out = (float*)d_out;

  char* ws = (char*)d_ws;
  bf16*  hsb   = (bf16*)(ws + 0);
  bf16*  wb    = (bf16*)(ws + 16777216);
  float* S     = (float*)(ws + 0);           // overlays hsb+wb (dead after gemm1)
  bf16*  ybuf  = (bf16*)(ws + 0);            // overlays S (dead after recur)
  bf16*  owb   = (bf16*)(ws + 35127296);     // overlays upper wb (dead after gemm1)
  bf16*  proj  = (bf16*)(ws + 51904512);
  bf16*  conv  = (bf16*)(ws + 122159104);
  float* dtraw = (float*)(ws + 157810688);
  float* dtb   = (float*)(ws + 158859264);
  float* cumA  = (float*)(ws + 159907840);
  float* G     = (float*)(ws + 160956416);
  float* P     = (float*)(ws + 165150720);
  bf16*  gb    = (bf16*)(ws + 165150720);    // overlays P (dead after y_kernel)

  cvt_bf16_kernel<<<4096, 256, 0, stream>>>(hs, hsb, (long)ROWS * HIDDEN, (long)ROWS * HIDDEN);
  cvt_bf16_kernel<<<8576, 256, 0, stream>>>(ipw, wb, (long)PROJ_PAD * HIDDEN, (long)PROJ_N * HIDDEN);

  // gemm1: WPE=4 occupancy experiment (4 blocks/CU cap; 120 unified regs fit)
  gemm_bt_kernel<4><<<(PROJ_PAD / 128) * (ROWS / 128), 256, 0, stream>>>(
      hsb, wb, ipb, proj, nullptr, dtraw, ROWS, PROJ_PAD, HIDDEN, PROJ_N, DT_COL0);

  cvt_bf16_kernel<<<4096, 256, 0, stream>>>(opw, owb, (long)HIDDEN * INTER, (long)HIDDEN * INTER);

  conv_silu_kernel<<<8704, 256, 0, stream>>>(proj, cw, conv);

  dt_scan_kernel<<<1024, 256, 0, stream>>>(dtraw, dtbi, alog, dtb, cumA);

  g_kernel<<<dim3(16, 4, 4), 256, 0, stream>>>(conv, G);

  states_kernel<<<1024, 256, 0, stream>>>(conv, dtb, cumA, S);

  recur_kernel<<<dim3(128, 4), 256, 0, stream>>>(S, cumA, P);

  y_kernel<<<1024, 256, 0, stream>>>(conv, dtb, cumA, G, P, Dp, ybuf);

  rmsnorm_kernel<<<4096, 256, 0, stream>>>(ybuf, proj, nw, gb);

  // gemm2: WPE=2 control (round-0 codegen)
  gemm_bt_kernel<2><<<(HIDDEN / 128) * (ROWS / 128), 256, 0, stream>>>(
      gb, owb, opb, nullptr, out, nullptr, ROWS, HIDDEN, INTER, HIDDEN, 1 << 30);
}

// Round 8
// 636.472 us; speedup vs baseline: 1.0521x; 1.0521x over previous
//
#include <hip/hip_runtime.h>

typedef __bf16 bf16;
typedef __bf16 bf16x8 __attribute__((ext_vector_type(8)));
typedef __bf16 bf16x4 __attribute__((ext_vector_type(4)));
typedef float  floatx4 __attribute__((ext_vector_type(4)));

#define HIDDEN   2048
#define NUMH     64
#define HDIM     64
#define STATE    128
#define INTER    4096
#define CONV_DIM 4352
#define PROJ_N   8512
#define PROJ_PAD 8576
#define SEQ      2048
#define BATCH    2
#define CHUNK    256
#define NCHUNK   8
#define ROWS     4096   // BATCH*SEQ
#define DT_COL0  8448   // INTER + CONV_DIM

// async global->LDS, 16B per lane, LDS dest = wave-uniform base + lane*16
#define GLDS(gp, lp) __builtin_amdgcn_global_load_lds(                      \
    (const __attribute__((address_space(1))) void*)(gp),                    \
    (__attribute__((address_space(3))) void*)(lp), 16, 0, 0)

// Bank-conflict swizzle for [row][32]-elem bf16 LDS tiles: XOR the 8-col
// chunk index with (row>>3)&3. Bijective per row, keeps 16B chunks intact
// (b128 reads stay aligned). Write: addr = SWZ(row, col>>3) + (col&7).
// Read (b128 at chunk q): ptr = buf + SWZ(row, q).
// Breaks the 32-way collapse in transposed staging (states sBT: all 64
// lanes hit 2 banks without this) and cuts 8-way fragment-read aliasing.
#define SWZ(row, chunk) ((row) * 32 + ((((chunk) ^ ((row) >> 3)) & 3) << 3))

// ------------------------------------------------- f32 -> bf16 (8/thread)
__global__ __launch_bounds__(256) void cvt_bf16_kernel(
    const float* __restrict__ in, bf16* __restrict__ out, long n, long srcn) {
  long i = ((long)blockIdx.x * 256 + threadIdx.x) * 8;
  if (i >= n) return;
  if (i + 7 < srcn) {
    const float4* p = (const float4*)(in + i);
    float4 a = p[0], b = p[1];
    bf16x8 o;
    o[0] = (bf16)a.x; o[1] = (bf16)a.y; o[2] = (bf16)a.z; o[3] = (bf16)a.w;
    o[4] = (bf16)b.x; o[5] = (bf16)b.y; o[6] = (bf16)b.z; o[7] = (bf16)b.w;
    *(bf16x8*)(out + i) = o;
  } else {
    for (int j = 0; j < 8; j++) {
      float v = (i + j < srcn) ? in[i + j] : 0.f;
      out[i + j] = (bf16)v;
    }
  }
}

// ------------------------------------------------------- bf16 MFMA GEMM (BT)
// round-0 proven m97-structure kernel (control: do not touch).
__global__ __launch_bounds__(256, 2) void gemm_bt_kernel(
    const bf16* __restrict__ A, const bf16* __restrict__ B,
    const float* __restrict__ bias, bf16* __restrict__ Cb,
    float* __restrict__ Cf, float* __restrict__ ds,
    int M, int N, int K, int bias_n, int dt0) {
  __shared__ __align__(16) bf16 lA[2 * 128 * 32];
  __shared__ __align__(16) bf16 lB[2 * 128 * 32];
  const int tid  = threadIdx.x;
  const int lane = tid & 63;
  const int wave = tid >> 6;
  const int gm = M >> 7;
  const int id = blockIdx.x;
  const int xcd = id & 7;
  const int j = id >> 3;
  const int mstripe = gm >> 3;
  const int mb = xcd * mstripe + (j % mstripe);
  const int nb = j / mstripe;
  const int m0 = mb * 128;
  const int n0 = nb * 128;
  const int wm = (wave >> 1) * 64;
  const int wn = (wave & 1) * 64;
  const int q  = lane >> 4;     // 0..3
  const int ln = lane & 15;
  const int r0 = tid >> 2;      // 0..63
  const int c0 = (tid & 3) * 8; // 0,8,16,24

  floatx4 acc[4][4] = {};

  const bf16* Ap = A + (long)(m0 + r0) * K + c0;
  const bf16* Bp = B + (long)(n0 + r0) * K + c0;
  bf16* lAw = lA + wave * 512;   // wave-uniform LDS base (lane*16B appended)
  bf16* lBw = lB + wave * 512;

  for (int k0 = 0; k0 < K; k0 += 64) {
    __syncthreads();
    GLDS(Ap + k0, lAw);
    GLDS(Ap + (long)64 * K + k0, lAw + 2048);
    GLDS(Ap + k0 + 32, lAw + 4096);
    GLDS(Ap + (long)64 * K + k0 + 32, lAw + 6144);
    GLDS(Bp + k0, lBw);
    GLDS(Bp + (long)64 * K + k0, lBw + 2048);
    GLDS(Bp + k0 + 32, lBw + 4096);
    GLDS(Bp + (long)64 * K + k0 + 32, lBw + 6144);
    __syncthreads();
#pragma unroll
    for (int kc = 0; kc < 2; kc++) {
      bf16x8 af[4], bg[4];
#pragma unroll
      for (int i = 0; i < 4; i++) {
        af[i] = *(const bf16x8*)(lA + kc * 4096 + (wm + i * 16 + ln) * 32 + q * 8);
        bg[i] = *(const bf16x8*)(lB + kc * 4096 + (wn + i * 16 + ln) * 32 + q * 8);
      }
#pragma unroll
      for (int mi = 0; mi < 4; mi++)
#pragma unroll
        for (int ni = 0; ni < 4; ni++)
          acc[mi][ni] = __builtin_amdgcn_mfma_f32_16x16x32_bf16(
              af[mi], bg[ni], acc[mi][ni], 0, 0, 0);
    }
  }

#pragma unroll
  for (int mi = 0; mi < 4; mi++) {
#pragma unroll
    for (int ni = 0; ni < 4; ni++) {
      int col = n0 + wn + ni * 16 + ln;
      float bv = (col < bias_n) ? bias[col] : 0.f;
#pragma unroll
      for (int r = 0; r < 4; r++) {
        int row = m0 + wm + mi * 16 + q * 4 + r;
        float v = acc[mi][ni][r] + bv;
        if (Cb) Cb[(long)row * N + col] = (bf16)v;
        else    Cf[(long)row * N + col] = v;
        if (ds && col >= dt0 && col < dt0 + 64)
          ds[(long)row * 64 + (col - dt0)] = v;
      }
    }
  }
}

// ------------------------------------------- causal conv4 + SiLU (8/thread)
__global__ __launch_bounds__(256) void conv_silu_kernel(
    const bf16* __restrict__ proj, const float* __restrict__ cw,
    bf16* __restrict__ out) {
  long i = ((long)blockIdx.x * 256 + threadIdx.x) * 8;
  if (i >= (long)ROWS * CONV_DIM) return;
  int ch = (int)(i % CONV_DIM);        // multiple of 8 (CONV_DIM % 8 == 0)
  long bl = i / CONV_DIM;
  int l = (int)(bl & (SEQ - 1));
  const bf16* p = proj + bl * PROJ_PAD + INTER + ch;
  float a[8] = {};
#pragma unroll
  for (int tap = 0; tap < 4; tap++) {
    int back = 3 - tap;
    if (l >= back) {
      bf16x8 v = *(const bf16x8*)(p - (long)back * PROJ_PAD);
#pragma unroll
      for (int j = 0; j < 8; j++) a[j] += (float)v[j] * cw[(ch + j) * 4 + tap];
    }
  }
  bf16x8 o;
#pragma unroll
  for (int j = 0; j < 8; j++) {
    float s = a[j] / (1.f + expf(-a[j]));
    o[j] = (bf16)s;
  }
  *(bf16x8*)(out + i) = o;
}

// ---------------------------------------------- dt softplus + per-chunk scan
__global__ __launch_bounds__(256) void dt_scan_kernel(
    const float* __restrict__ dtraw, const float* __restrict__ dt_bias,
    const float* __restrict__ A_log, float* __restrict__ dtb,
    float* __restrict__ cumA) {
  int idx = blockIdx.x;
  int c = idx & 7, h = (idx >> 3) & 63, b = idx >> 9;
  int s = threadIdx.x;
  long row = (long)b * SEQ + c * CHUNK + s;
  float x = dtraw[row * NUMH + h] + dt_bias[h];
  float dt = (x > 20.f) ? x : log1pf(expf(x));
  dtb[row * NUMH + h] = dt;
  float dA = -expf(A_log[h]) * dt;
  __shared__ float sc[256];
  sc[s] = dA;
  __syncthreads();
  for (int off = 1; off < 256; off <<= 1) {
    float v = (s >= off) ? sc[s - off] : 0.f;
    __syncthreads();
    sc[s] += v;
    __syncthreads();
  }
  cumA[(long)idx * 256 + s] = sc[s];
}

// ------------------------------------------------- G = C @ B^T  (MFMA)
__global__ __launch_bounds__(256, 2) void g_kernel(
    const bf16* __restrict__ conv, float* __restrict__ G) {
  int bc = blockIdx.x, tt = blockIdx.y, sb = blockIdx.z;
  if (sb > tt) return;  // upper triangle never read
  int b = bc >> 3, c = bc & 7;
  int tid = threadIdx.x, lane = tid & 63, w = tid >> 6;
  int q = lane >> 4, ln = lane & 15;
  __shared__ __align__(16) bf16 sCg[4 * 64 * 32];  // row=(kc*64+t), swizzled cols
  __shared__ __align__(16) bf16 sBg[4 * 64 * 32];
  long rowBase = (long)b * SEQ + c * CHUNK;
  for (int i = tid; i < 1024; i += 256) {
    int r = i >> 4, n0 = (i & 15) * 8;
    int row = (n0 >> 5) * 64 + r;
    int base = SWZ(row, (n0 & 31) >> 3);
    bf16x8 cv = *(const bf16x8*)(conv + (rowBase + tt * 64 + r) * CONV_DIM + INTER + STATE + n0);
    *(bf16x8*)(sCg + base) = cv;
    bf16x8 bv = *(const bf16x8*)(conv + (rowBase + sb * 64 + r) * CONV_DIM + INTER + n0);
    *(bf16x8*)(sBg + base) = bv;
  }
  __syncthreads();
  floatx4 acc[4] = {};
#pragma unroll
  for (int kc = 0; kc < 4; kc++) {
    bf16x8 af = *(const bf16x8*)(sCg + SWZ(kc * 64 + w * 16 + ln, q));
#pragma unroll
    for (int ni = 0; ni < 4; ni++) {
      bf16x8 bg = *(const bf16x8*)(sBg + SWZ(kc * 64 + ni * 16 + ln, q));
      acc[ni] = __builtin_amdgcn_mfma_f32_16x16x32_bf16(af, bg, acc[ni], 0, 0, 0);
    }
  }
  float* Gb = G + ((long)bc << 16);
#pragma unroll
  for (int ni = 0; ni < 4; ni++) {
    int s = sb * 64 + ni * 16 + ln;
#pragma unroll
    for (int r = 0; r < 4; r++) {
      int t = tt * 64 + w * 16 + q * 4 + r;
      Gb[(long)t * 256 + s] = acc[ni][r];
    }
  }
}

// --------------------------------------- per-chunk states S = B^T·(x·w) MFMA
__global__ __launch_bounds__(256, 2) void states_kernel(
    const bf16* __restrict__ conv, const float* __restrict__ dtb,
    const float* __restrict__ cumA, float* __restrict__ S) {
  int idx = blockIdx.x;  // ((b*8+c)*64+h)
  int h = idx & 63, c = (idx >> 6) & 7, b = idx >> 9;
  int tid = threadIdx.x, lane = tid & 63, w = tid >> 6;
  int q = lane >> 4, ln = lane & 15;
  __shared__ __align__(16) bf16 sBT[2 * 128 * 32];  // row=(kc*128+n), swz cols
  __shared__ __align__(16) bf16 sXT[2 * 64 * 32];   // row=(kc*64+p),  swz cols
  long caBase = ((long)(b * 64 + h) * 8 + c) * 256;
  float aLast = cumA[caBase + 255];
  long rowBase = (long)b * SEQ + c * CHUNK;
  floatx4 acc[2][4] = {};
  for (int s0 = 0; s0 < 256; s0 += 64) {
    __syncthreads();
    for (int i = tid; i < 1024; i += 256) {
      int sl = i >> 4, n0 = (i & 15) * 8;
      bf16x8 v = *(const bf16x8*)(conv + (rowBase + s0 + sl) * CONV_DIM + INTER + n0);
      int kc = sl >> 5, ccq = (sl & 31) >> 3, c3 = sl & 7;
#pragma unroll
      for (int jj = 0; jj < 8; jj++)
        sBT[SWZ(kc * 128 + n0 + jj, ccq) + c3] = v[jj];
    }
    for (int i = tid; i < 512; i += 256) {
      int sl = i >> 3, p0 = (i & 7) * 8;
      long row = rowBase + s0 + sl;
      float wgt = __expf(aLast - cumA[caBase + s0 + sl]) * dtb[row * NUMH + h];
      bf16x8 v = *(const bf16x8*)(conv + row * CONV_DIM + h * HDIM + p0);
      int kc = sl >> 5, ccq = (sl & 31) >> 3, c3 = sl & 7;
#pragma unroll
      for (int jj = 0; jj < 8; jj++)
        sXT[SWZ(kc * 64 + p0 + jj, ccq) + c3] = (bf16)((float)v[jj] * wgt);
    }
    __syncthreads();
#pragma unroll
    for (int kc = 0; kc < 2; kc++) {
      bf16x8 af[2], bg[4];
#pragma unroll
      for (int mi = 0; mi < 2; mi++)
        af[mi] = *(const bf16x8*)(sBT + SWZ(kc * 128 + w * 32 + mi * 16 + ln, q));
#pragma unroll
      for (int ni = 0; ni < 4; ni++)
        bg[ni] = *(const bf16x8*)(sXT + SWZ(kc * 64 + ni * 16 + ln, q));
#pragma unroll
      for (int mi = 0; mi < 2; mi++)
#pragma unroll
        for (int ni = 0; ni < 4; ni++)
          acc[mi][ni] = __builtin_amdgcn_mfma_f32_16x16x32_bf16(
              af[mi], bg[ni], acc[mi][ni], 0, 0, 0);
    }
  }
  float* Sp = S + ((long)idx << 13);
#pragma unroll
  for (int mi = 0; mi < 2; mi++)
#pragma unroll
    for (int ni = 0; ni < 4; ni++) {
      int p = ni * 16 + ln;
#pragma unroll
      for (int r = 0; r < 4; r++) {
        int n = w * 32 + mi * 16 + q * 4 + r;
        Sp[n * 64 + p] = acc[mi][ni][r];
      }
    }
}

// ---------------------------------------- inter-chunk recurrence (b,h,kq)
__global__ __launch_bounds__(256) void recur_kernel(
    const float* __restrict__ S, const float* __restrict__ cumA,
    float* __restrict__ P) {
  int bh = blockIdx.x, kq = blockIdx.y;
  int b = bh >> 6, h = bh & 63;
  int tid = threadIdx.x;
  float p[8];
#pragma unroll
  for (int k = 0; k < 8; k++) p[k] = 0.f;
  for (int c = 0; c < 8; c++) {
    long blk = ((long)(b * 8 + c) * 64 + h) << 13;
#pragma unroll
    for (int k = 0; k < 8; k++) P[blk + (kq * 8 + k) * 256 + tid] = p[k];
    float e = __expf(cumA[((long)bh * 8 + c) * 256 + 255]);
#pragma unroll
    for (int k = 0; k < 8; k++) p[k] = S[blk + (kq * 8 + k) * 256 + tid] + e * p[k];
  }
}

// ------------------------------------------------ Y = diag + off + D*x (MFMA)
// off-diag decay factored: exp(cAt-cAs) = exp(cAt-cAend(sb)) * sE[s], both <=1
__global__ __launch_bounds__(256, 2) void y_kernel(
    const bf16* __restrict__ conv, const float* __restrict__ dtb,
    const float* __restrict__ cumA, const float* __restrict__ G,
    const float* __restrict__ P, const float* __restrict__ D,
    bf16* __restrict__ ybuf) {
  int idx = blockIdx.x;  // ((b*8+c)*64+h)
  int h = idx & 63, c = (idx >> 6) & 7, b = idx >> 9;
  int tid = threadIdx.x, lane = tid & 63, w = tid >> 6;
  int q = lane >> 4, ln = lane & 15;
  __shared__ __align__(16) bf16 sPT[128 * 64];   // row=(n>>5)*64+p, swz cols
  __shared__ __align__(16) bf16 sXT[256 * 64];   // row=(s>>5)*64+p, swz cols
  __shared__ float scA[256];
  __shared__ float sE[256];                      // exp(cA[s|63] - cA[s]) <= 1
  long caBase = ((long)(b * 64 + h) * 8 + c) * 256;
  long rowBase = (long)b * SEQ + c * CHUNK;
  const float* Gbase = G + ((long)(b * 8 + c) << 16);

  float myA = cumA[caBase + tid];
  scA[tid] = myA;
  {
    const float* Pblk = P + ((long)idx << 13);
    int n = tid >> 1;
    int p0 = (tid & 1) * 32;
    int nc = (n >> 5) * 64, nk = n & 31;
    int ccq = nk >> 3, c3 = nk & 7;
#pragma unroll
    for (int pp = 0; pp < 32; pp += 4) {
      floatx4 v = *(const floatx4*)(Pblk + n * 64 + p0 + pp);
#pragma unroll
      for (int j = 0; j < 4; j++)
        sPT[SWZ(nc + p0 + pp + j, ccq) + c3] = (bf16)v[j];
    }
  }
  {
    int s = tid;
    long row = rowBase + s;
    float dt = dtb[row * NUMH + h];
    int sc = (s >> 5) * 64, sk = s & 31;
    int ccq = sk >> 3, c3 = sk & 7;
    const bf16* xr = conv + row * CONV_DIM + h * HDIM;
#pragma unroll
    for (int p0 = 0; p0 < 64; p0 += 8) {
      bf16x8 xv = *(const bf16x8*)(xr + p0);
#pragma unroll
      for (int j = 0; j < 8; j++)
        sXT[SWZ(sc + p0 + j, ccq) + c3] = (bf16)((float)xv[j] * dt);
    }
  }
  __syncthreads();
  sE[tid] = __expf(scA[tid | 63] - myA);

  floatx4 acc[4][4] = {};

  // phase 1: Y_off = C @ P^T
  const bf16* Cbase = conv + (rowBase + w * 64) * CONV_DIM + INTER + STATE;
  for (int k0 = 0; k0 < 128; k0 += 32) {
    bf16x8 af[4], bg[4];
#pragma unroll
    for (int mi = 0; mi < 4; mi++)
      af[mi] = *(const bf16x8*)(Cbase + (long)(mi * 16 + ln) * CONV_DIM + k0 + q * 8);
#pragma unroll
    for (int ni = 0; ni < 4; ni++)
      bg[ni] = *(const bf16x8*)(sPT + SWZ((k0 >> 5) * 64 + ni * 16 + ln, q));
#pragma unroll
    for (int mi = 0; mi < 4; mi++)
#pragma unroll
      for (int ni = 0; ni < 4; ni++)
        acc[mi][ni] = __builtin_amdgcn_mfma_f32_16x16x32_bf16(
            af[mi], bg[ni], acc[mi][ni], 0, 0, 0);
  }
#pragma unroll
  for (int mi = 0; mi < 4; mi++)
#pragma unroll
    for (int r = 0; r < 4; r++) {
      float e = __expf(scA[w * 64 + mi * 16 + q * 4 + r]);
#pragma unroll
      for (int ni = 0; ni < 4; ni++) acc[mi][ni][r] *= e;
    }
  __syncthreads();  // sE visible to all waves

  // phase 2a: off-diagonal s-blocks (factored decay, no per-element expf)
  for (int sb = 0; sb < w; sb++) {
    float Rm[4];
#pragma unroll
    for (int mi = 0; mi < 4; mi++)
      Rm[mi] = __expf(scA[w * 64 + mi * 16 + ln] - scA[sb * 64 + 63]);
#pragma unroll
    for (int kk = 0; kk < 64; kk += 32) {
      int s0 = sb * 64 + kk;
      bf16x8 af[4], bg[4];
#pragma unroll
      for (int mi = 0; mi < 4; mi++) {
        int t = w * 64 + mi * 16 + ln;
        const float* Gr = Gbase + (long)t * 256 + s0 + q * 8;
        floatx4 g0 = *(const floatx4*)Gr;
        floatx4 g1 = *(const floatx4*)(Gr + 4);
        bf16x8 m;
#pragma unroll
        for (int j = 0; j < 4; j++)
          m[j] = (bf16)(g0[j] * Rm[mi] * sE[s0 + q * 8 + j]);
#pragma unroll
        for (int j = 4; j < 8; j++)
          m[j] = (bf16)(g1[j - 4] * Rm[mi] * sE[s0 + q * 8 + j]);
        af[mi] = m;
      }
#pragma unroll
      for (int ni = 0; ni < 4; ni++)
        bg[ni] = *(const bf16x8*)(sXT + SWZ((s0 >> 5) * 64 + ni * 16 + ln, q));
#pragma unroll
      for (int mi = 0; mi < 4; mi++)
#pragma unroll
        for (int ni = 0; ni < 4; ni++)
          acc[mi][ni] = __builtin_amdgcn_mfma_f32_16x16x32_bf16(
              af[mi], bg[ni], acc[mi][ni], 0, 0, 0);
    }
  }

  // phase 2b: diagonal s-block (per-element expf + causal mask)
  {
    int sb = w;
#pragma unroll
    for (int kk = 0; kk < 64; kk += 32) {
      int s0 = sb * 64 + kk;
      bf16x8 af[4], bg[4];
#pragma unroll
      for (int mi = 0; mi < 4; mi++) {
        int t = w * 64 + mi * 16 + ln;
        float cAt = scA[t];
        const float* Gr = Gbase + (long)t * 256 + s0 + q * 8;
        floatx4 g0 = *(const floatx4*)Gr;
        floatx4 g1 = *(const floatx4*)(Gr + 4);
        bf16x8 m;
#pragma unroll
        for (int j = 0; j < 4; j++) {
          int s = s0 + q * 8 + j;
          float v = g0[j] * __expf(cAt - scA[s]);
          m[j] = (bf16)((s <= t) ? v : 0.f);
        }
#pragma unroll
        for (int j = 4; j < 8; j++) {
          int s = s0 + q * 8 + j;
          float v = g1[j - 4] * __expf(cAt - scA[s]);
          m[j] = (bf16)((s <= t) ? v : 0.f);
        }
        af[mi] = m;
      }
#pragma unroll
      for (int ni = 0; ni < 4; ni++)
        bg[ni] = *(const bf16x8*)(sXT + SWZ((s0 >> 5) * 64 + ni * 16 + ln, q));
#pragma unroll
      for (int mi = 0; mi < 4; mi++)
#pragma unroll
        for (int ni = 0; ni < 4; ni++)
          acc[mi][ni] = __builtin_amdgcn_mfma_f32_16x16x32_bf16(
              af[mi], bg[ni], acc[mi][ni], 0, 0, 0);
    }
  }

  float d = D[h];
#pragma unroll
  for (int mi = 0; mi < 4; mi++)
#pragma unroll
    for (int ni = 0; ni < 4; ni++) {
      int col = ni * 16 + ln;
#pragma unroll
      for (int r = 0; r < 4; r++) {
        long row = rowBase + w * 64 + mi * 16 + q * 4 + r;
        float xv = (float)conv[row * CONV_DIM + h * HDIM + col];
        ybuf[row * INTER + h * HDIM + col] = (bf16)(acc[mi][ni][r] + d * xv);
      }
    }
}

// --------------------------------- gated RMSNorm->bf16 (vectorized bf16x8)
__global__ __launch_bounds__(256) void rmsnorm_kernel(
    const bf16* __restrict__ ybuf, const bf16* __restrict__ proj,
    const float* __restrict__ nw, bf16* __restrict__ gb) {
  long row = blockIdx.x;
  int tid = threadIdx.x;
  float gv[16];
  float ss = 0.f;
#pragma unroll
  for (int h = 0; h < 2; h++) {
    int i = h * 2048 + tid * 8;
    bf16x8 yv = *(const bf16x8*)(ybuf + row * INTER + i);
    bf16x8 gt = *(const bf16x8*)(proj + row * PROJ_PAD + i);
#pragma unroll
    for (int j = 0; j < 8; j++) {
      float y = (float)yv[j];
      float g = (float)gt[j];
      float gg = y * (g / (1.f + expf(-g)));
      gv[h * 8 + j] = gg;
      ss += gg * gg;
    }
  }
#pragma unroll
  for (int off = 32; off > 0; off >>= 1) ss += __shfl_down(ss, off, 64);
  __shared__ float red[4];
  if ((tid & 63) == 0) red[tid >> 6] = ss;
  __syncthreads();
  float tot = red[0] + red[1] + red[2] + red[3];
  float scale = rsqrtf(tot * (1.f / 4096.f) + 1e-5f);
#pragma unroll
  for (int h = 0; h < 2; h++) {
    int i = h * 2048 + tid * 8;
    bf16x8 o;
#pragma unroll
    for (int j = 0; j < 8; j++)
      o[j] = (bf16)(gv[h * 8 + j] * scale * nw[i + j]);
    *(bf16x8*)(gb + row * INTER + i) = o;
  }
}

// ============================================================== launch
extern "C" void kernel_launch(void* const* d_in, const int* in_sizes, int n_in,
                              void* d_out, int out_size, void* d_ws, size_t ws_size,
                              hipStream_t stream) {
  const float* hs   = (const float*)d_in[0];
  const float* ipw  = (const float*)d_in[1];
  const float* ipb  = (const float*)d_in[2];
  const float* cw   = (const float*)d_in[3];
  const float* dtbi = (const float*)d_in[4];
  const float* alog = (const float*)d_in[5];
  const float* Dp   = (const float*)d_in[6];
  const float* nw   = (const float*)d_in[7];
  const float* opw  = (const float*)d_in[8];
  const float* opb  = (const float*)d_in[9];
  float* out = (float*)d_out;

  char* ws = (char*)d_ws;
  bf16*  hsb   = (bf16*)(ws + 0);
  bf16*  wb    = (bf16*)(ws + 16777216);
  float* S     = (float*)(ws + 0);           // overlays hsb+wb (dead after gemm1)
  bf16*  ybuf  = (bf16*)(ws + 0);            // overlays S (dead after recur)
  bf16*  owb   = (bf16*)(ws + 35127296);     // overlays upper wb (dead after gemm1)
  bf16*  proj  = (bf16*)(ws + 51904512);
  bf16*  conv  = (bf16*)(ws + 122159104);
  float* dtraw = (float*)(ws + 157810688);
  float* dtb   = (float*)(ws + 158859264);
  float* cumA  = (float*)(ws + 159907840);
  float* G     = (float*)(ws + 160956416);
  float* P     = (float*)(ws + 165150720);
  bf16*  gb    = (bf16*)(ws + 165150720);    // overlays P (dead after y_kernel)

  cvt_bf16_kernel<<<4096, 256, 0, stream>>>(hs, hsb, (long)ROWS * HIDDEN, (long)ROWS * HIDDEN);
  cvt_bf16_kernel<<<8576, 256, 0, stream>>>(ipw, wb, (long)PROJ_PAD * HIDDEN, (long)PROJ_N * HIDDEN);

  gemm_bt_kernel<<<(PROJ_PAD / 128) * (ROWS / 128), 256, 0, stream>>>(
      hsb, wb, ipb, proj, nullptr, dtraw, ROWS, PROJ_PAD, HIDDEN, PROJ_N, DT_COL0);

  cvt_bf16_kernel<<<4096, 256, 0, stream>>>(opw, owb, (long)HIDDEN * INTER, (long)HIDDEN * INTER);

  conv_silu_kernel<<<8704, 256, 0, stream>>>(proj, cw, conv);

  dt_scan_kernel<<<1024, 256, 0, stream>>>(dtraw, dtbi, alog, dtb, cumA);

  g_kernel<<<dim3(16, 4, 4), 256, 0, stream>>>(conv, G);

  states_kernel<<<1024, 256, 0, stream>>>(conv, dtb, cumA, S);

  recur_kernel<<<dim3(128, 4), 256, 0, stream>>>(S, cumA, P);

  y_kernel<<<1024, 256, 0, stream>>>(conv, dtb, cumA, G, P, Dp, ybuf);

  rmsnorm_kernel<<<4096, 256, 0, stream>>>(ybuf, proj, nw, gb);

  gemm_bt_kernel<<<(HIDDEN / 128) * (ROWS / 128), 256, 0, stream>>>(
      gb, owb, opb, nullptr, out, nullptr, ROWS, HIDDEN, INTER, HIDDEN, 1 << 30);
}